// Round 1
// baseline (290.722 us; speedup 1.0000x reference)
//
#include <hip/hip_runtime.h>

#define BINS 10

// Per-element work: gradient magnitude -> bin, BCE loss, predicated
// accumulation into per-thread register histograms (no atomics, no
// divergence; statically-indexed arrays stay in VGPRs).
__device__ __forceinline__ void accum_elem(float xx, float tt,
                                           float* __restrict__ sum,
                                           unsigned* __restrict__ cnt) {
    float g = fabsf(xx - tt);
    // reference: floor(g * (10 - 1e-4)); identical fp32 ops -> bit-match
    int b = (int)(g * 9.9999f);
    b = b > (BINS - 1) ? (BINS - 1) : b;
    float loss = -(tt * __logf(xx) + (1.0f - tt) * __logf(1.0f - xx));
#pragma unroll
    for (int k = 0; k < BINS; ++k) {
        bool m = (b == k);
        sum[k] += m ? loss : 0.0f;
        cnt[k] += m ? 1u : 0u;
    }
}

// ATOMIC=false: write per-block partials to psum/pcnt[block*BINS+k].
// ATOMIC=true : atomically accumulate into psum/pcnt[k] (80 B total),
//               used when the workspace can't hold per-block partials.
template <bool ATOMIC>
__global__ __launch_bounds__(256) void ghm_partial(
    const float* __restrict__ x, const float* __restrict__ t,
    float* __restrict__ psum, unsigned* __restrict__ pcnt,
    int n4, long long n_total)
{
    float sum[BINS];
    unsigned cnt[BINS];
#pragma unroll
    for (int k = 0; k < BINS; ++k) { sum[k] = 0.0f; cnt[k] = 0u; }

    const float4* __restrict__ x4 = (const float4*)x;
    const float4* __restrict__ t4 = (const float4*)t;
    int tid = blockIdx.x * blockDim.x + threadIdx.x;
    int stride = gridDim.x * blockDim.x;

    // grid-stride over float4 pairs, 2x unrolled: 64 B of independent loads
    // in flight per lane per iteration (MLP) before the VALU chain.
    int i = tid;
    for (; i + stride < n4; i += 2 * stride) {
        float4 xa = x4[i];
        float4 ta = t4[i];
        float4 xb = x4[i + stride];
        float4 tb = t4[i + stride];
        accum_elem(xa.x, ta.x, sum, cnt);
        accum_elem(xa.y, ta.y, sum, cnt);
        accum_elem(xa.z, ta.z, sum, cnt);
        accum_elem(xa.w, ta.w, sum, cnt);
        accum_elem(xb.x, tb.x, sum, cnt);
        accum_elem(xb.y, tb.y, sum, cnt);
        accum_elem(xb.z, tb.z, sum, cnt);
        accum_elem(xb.w, tb.w, sum, cnt);
    }
    if (i < n4) {
        float4 xa = x4[i];
        float4 ta = t4[i];
        accum_elem(xa.x, ta.x, sum, cnt);
        accum_elem(xa.y, ta.y, sum, cnt);
        accum_elem(xa.z, ta.z, sum, cnt);
        accum_elem(xa.w, ta.w, sum, cnt);
    }
    // scalar tail (N not divisible by 4) — handled by low global tids
    long long tail_base = (long long)n4 * 4;
    long long rem = n_total - tail_base;
    if ((long long)tid < rem) {
        accum_elem(x[tail_base + tid], t[tail_base + tid], sum, cnt);
    }

    // wave(64) shuffle reduction of 10 sums + 10 counts
#pragma unroll
    for (int k = 0; k < BINS; ++k) {
#pragma unroll
        for (int off = 32; off > 0; off >>= 1) {
            sum[k] += __shfl_down(sum[k], off, 64);
            cnt[k] += (unsigned)__shfl_down((int)cnt[k], off, 64);
        }
    }

    __shared__ float s_sum[4][BINS];
    __shared__ unsigned s_cnt[4][BINS];
    int lane = threadIdx.x & 63;
    int wv = threadIdx.x >> 6;
    if (lane == 0) {
#pragma unroll
        for (int k = 0; k < BINS; ++k) { s_sum[wv][k] = sum[k]; s_cnt[wv][k] = cnt[k]; }
    }
    __syncthreads();
    if (threadIdx.x < BINS) {
        float s = 0.0f;
        unsigned c = 0u;
#pragma unroll
        for (int w = 0; w < 4; ++w) { s += s_sum[w][threadIdx.x]; c += s_cnt[w][threadIdx.x]; }
        if (ATOMIC) {
            atomicAdd(&psum[threadIdx.x], s);
            atomicAdd(&pcnt[threadIdx.x], c);
        } else {
            psum[(size_t)blockIdx.x * BINS + threadIdx.x] = s;
            pcnt[(size_t)blockIdx.x * BINS + threadIdx.x] = c;
        }
    }
}

// Zero the 80 B atomic accumulator region (atomic fallback path only).
__global__ void ghm_zero(float* psum, unsigned* pcnt) {
    if (threadIdx.x < BINS) { psum[threadIdx.x] = 0.0f; pcnt[threadIdx.x] = 0u; }
}

// Single-block finalize: reduce per-block partials, compute beta, weighted sum.
__global__ __launch_bounds__(256) void ghm_final(
    const float* __restrict__ psum, const unsigned* __restrict__ pcnt,
    float* __restrict__ out, int nblocks, float Nf)
{
    float sum[BINS];
    unsigned cnt[BINS];
#pragma unroll
    for (int k = 0; k < BINS; ++k) { sum[k] = 0.0f; cnt[k] = 0u; }

    for (int i = threadIdx.x; i < nblocks; i += blockDim.x) {
#pragma unroll
        for (int k = 0; k < BINS; ++k) {
            sum[k] += psum[(size_t)i * BINS + k];
            cnt[k] += pcnt[(size_t)i * BINS + k];
        }
    }

#pragma unroll
    for (int k = 0; k < BINS; ++k) {
#pragma unroll
        for (int off = 32; off > 0; off >>= 1) {
            sum[k] += __shfl_down(sum[k], off, 64);
            cnt[k] += (unsigned)__shfl_down((int)cnt[k], off, 64);
        }
    }

    __shared__ float s_sum[4][BINS];
    __shared__ unsigned s_cnt[4][BINS];
    int lane = threadIdx.x & 63;
    int wv = threadIdx.x >> 6;
    if (lane == 0) {
#pragma unroll
        for (int k = 0; k < BINS; ++k) { s_sum[wv][k] = sum[k]; s_cnt[wv][k] = cnt[k]; }
    }
    __syncthreads();

    if (threadIdx.x == 0) {
        float tot_s[BINS];
        unsigned tot_c[BINS];
#pragma unroll
        for (int k = 0; k < BINS; ++k) {
            float s = 0.0f;
            unsigned c = 0u;
#pragma unroll
            for (int w = 0; w < 4; ++w) { s += s_sum[w][k]; c += s_cnt[w][k]; }
            tot_s[k] = s;
            tot_c[k] = c;
        }
        float nonempty = 0.0f;
#pragma unroll
        for (int k = 0; k < BINS; ++k) nonempty += (tot_c[k] > 0u) ? 1.0f : 0.0f;
        float total = 0.0f;
#pragma unroll
        for (int k = 0; k < BINS; ++k) {
            float gd = (float)tot_c[k] * nonempty;
            gd = gd < 1.0f ? 1.0f : gd;      // clip(gd, 1, None)
            float beta = Nf / gd;
            total += tot_s[k] * beta;
        }
        out[0] = total / Nf;   // mean
    }
}

extern "C" void kernel_launch(void* const* d_in, const int* in_sizes, int n_in,
                              void* d_out, int out_size, void* d_ws, size_t ws_size,
                              hipStream_t stream) {
    const float* x = (const float*)d_in[0];
    const float* t = (const float*)d_in[1];
    float* out = (float*)d_out;

    long long N = (long long)in_sizes[0];
    int n4 = (int)(N / 4);

    // 2048 blocks x 256 thr = 8192 waves = 32 waves/CU on 256 CUs: full
    // residency in a single dispatch pass. Grid size must NOT depend on
    // ws_size (the old version silently shrank the grid when ws was small,
    // which is the prime suspect for the 285 us latency-bound result).
    const int nblocks = 2048;
    const size_t per_block = (size_t)BINS * (sizeof(float) + sizeof(unsigned)); // 80 B

    if (ws_size >= (size_t)nblocks * per_block) {
        // Deterministic two-stage reduction (preferred).
        float* psum = (float*)d_ws;
        unsigned* pcnt = (unsigned*)(psum + (size_t)nblocks * BINS);
        ghm_partial<false><<<nblocks, 256, 0, stream>>>(x, t, psum, pcnt, n4, N);
        ghm_final<<<1, 256, 0, stream>>>(psum, pcnt, out, nblocks, (float)N);
    } else {
        // Atomic fallback: 80 B of workspace, 20 device-scope atomics/block.
        float* psum = (float*)d_ws;
        unsigned* pcnt = (unsigned*)(psum + BINS);
        ghm_zero<<<1, 64, 0, stream>>>(psum, pcnt);
        ghm_partial<true><<<nblocks, 256, 0, stream>>>(x, t, psum, pcnt, n4, N);
        ghm_final<<<1, 256, 0, stream>>>(psum, pcnt, out, 1, (float)N);
    }
}